// Round 11
// baseline (713.108 us; speedup 1.0000x reference)
//
#include <hip/hip_runtime.h>
#include <hip/hip_bf16.h>

#define DFEAT 64
#define SBSHIFT 9            // 512 rows per superbucket
#define SBROWS 512
#define CAPSHIFT 13          // 8192 edge slots per superbucket region
#define CAP 8192
#define CHUNK 8192           // edges per binA block (halves reservation depth vs 4096)
#define RPT 32               // CHUNK/256
#define CURPAD 16            // sbcursor padded: one counter per 64B line

typedef __attribute__((ext_vector_type(8))) unsigned short ushort8;

static __device__ __forceinline__ unsigned short f2bf(float f) {
    __hip_bfloat16 h = __float2bfloat16(f);   // RNE
    unsigned short u;
    __builtin_memcpy(&u, &h, 2);
    return u;
}

// ---------------------------------------------------------------------------
// 1) FUSED: binA (blocks [0,binABlocks) — FIRST, so its atomic-latency phase
//    overlaps the whole xw phase) || xw (remaining blocks).
//    LDS union: binA 2 KB (hist+cur), xw 16 KB (W).
//
//    binA: per-block LDS histogram over 512-row superbuckets -> one global
//    atomicAdd per (block,sb) on padded cursors reserves a contiguous run ->
//    direct scatter, payload = (row&511)<<17 | col. ei re-read in scatter
//    phase (L2-hot) to keep VGPRs low for the xw branch.
//    xw: Y[t] = feat[t] @ W in bf16, TWO rows per thread (rows bid*128+lrow
//    and +64) — shares every sW read across 2 FMA streams, halves block
//    count (782) and the fused kernel's drain tail.
// ---------------------------------------------------------------------------
__global__ __launch_bounds__(256) void binA_xw_kernel(
        const float* __restrict__ feat, const float* __restrict__ W,
        ushort8* __restrict__ Y, int n,
        const int* __restrict__ ei, int E,
        int* __restrict__ sbcursor, int* __restrict__ packed, int binABlocks) {
    __shared__ __align__(16) char smem[16384];

    if (blockIdx.x < binABlocks) {
        // ---------------- binA part ----------------
        int* hist = (int*)smem;        // 256
        int* cur  = hist + 256;        // 256
        int t = threadIdx.x;
        hist[t] = 0;
        __syncthreads();

        int base = blockIdx.x * CHUNK;
#pragma unroll 4
        for (int k = 0; k < RPT; k++) {
            int idx = base + k * 256 + t;
            if (idx < E) atomicAdd(&hist[ei[idx] >> SBSHIFT], 1);
        }
        __syncthreads();

        int h = hist[t];
        cur[t] = (h > 0) ? atomicAdd(&sbcursor[t * CURPAD], h) : 0;  // absolute base
        __syncthreads();

#pragma unroll 4
        for (int k = 0; k < RPT; k++) {
            int idx = base + k * 256 + t;
            if (idx < E) {
                int r = ei[idx];            // L2-hot re-read
                int c = ei[E + idx];
                int sb = r >> SBSHIFT;
                int pos = atomicAdd(&cur[sb], 1);
                if (pos < CAP)
                    packed[(sb << CAPSHIFT) + pos] = ((r & (SBROWS - 1)) << 17) | c;
            }
        }
    } else {
        // ---------------- xw part (2 rows/thread) ----------------
        float4* sW = (float4*)smem;    // 16 KB: W[k][j] as float4 over j
        for (int i = threadIdx.x; i < DFEAT * 16; i += blockDim.x)
            sW[i] = ((const float4*)W)[i];
        __syncthreads();

        int bid = blockIdx.x - binABlocks;
        int q = threadIdx.x & 3;
        int lrow = threadIdx.x >> 2;
        int lane = threadIdx.x & 63;
        int qbase = lane & ~3;
        int row0 = bid * 128 + lrow;
        int row1 = row0 + 64;

        float4 x0[4], x1[4];
        if (row0 < n) {
            const float4* xp = (const float4*)(feat + (size_t)row0 * DFEAT) + q * 4;
            x0[0] = xp[0]; x0[1] = xp[1]; x0[2] = xp[2]; x0[3] = xp[3];
        } else {
            x0[0] = x0[1] = x0[2] = x0[3] = make_float4(0.f, 0.f, 0.f, 0.f);
        }
        if (row1 < n) {
            const float4* xp = (const float4*)(feat + (size_t)row1 * DFEAT) + q * 4;
            x1[0] = xp[0]; x1[1] = xp[1]; x1[2] = xp[2]; x1[3] = xp[3];
        } else {
            x1[0] = x1[1] = x1[2] = x1[3] = make_float4(0.f, 0.f, 0.f, 0.f);
        }

        float4 a0[4], a1[4];
#pragma unroll
        for (int j = 0; j < 4; j++) {
            a0[j] = make_float4(0.f, 0.f, 0.f, 0.f);
            a1[j] = make_float4(0.f, 0.f, 0.f, 0.f);
        }

#pragma unroll
        for (int qp = 0; qp < 4; qp++) {
#pragma unroll
            for (int jj = 0; jj < 4; jj++) {
                float s0[4], s1[4];
                s0[0] = __shfl(x0[jj].x, qbase + qp);
                s0[1] = __shfl(x0[jj].y, qbase + qp);
                s0[2] = __shfl(x0[jj].z, qbase + qp);
                s0[3] = __shfl(x0[jj].w, qbase + qp);
                s1[0] = __shfl(x1[jj].x, qbase + qp);
                s1[1] = __shfl(x1[jj].y, qbase + qp);
                s1[2] = __shfl(x1[jj].z, qbase + qp);
                s1[3] = __shfl(x1[jj].w, qbase + qp);
                int k0 = qp * 16 + jj * 4;
#pragma unroll
                for (int c = 0; c < 4; c++) {
                    const float4* wrow = &sW[(k0 + c) * 16 + q * 4];
#pragma unroll
                    for (int j = 0; j < 4; j++) {
                        float4 w = wrow[j];
                        a0[j].x = fmaf(s0[c], w.x, a0[j].x);
                        a0[j].y = fmaf(s0[c], w.y, a0[j].y);
                        a0[j].z = fmaf(s0[c], w.z, a0[j].z);
                        a0[j].w = fmaf(s0[c], w.w, a0[j].w);
                        a1[j].x = fmaf(s1[c], w.x, a1[j].x);
                        a1[j].y = fmaf(s1[c], w.y, a1[j].y);
                        a1[j].z = fmaf(s1[c], w.z, a1[j].z);
                        a1[j].w = fmaf(s1[c], w.w, a1[j].w);
                    }
                }
            }
        }

        if (row0 < n) {
            ushort8 o0, o1;
            o0[0] = f2bf(a0[0].x); o0[1] = f2bf(a0[0].y);
            o0[2] = f2bf(a0[0].z); o0[3] = f2bf(a0[0].w);
            o0[4] = f2bf(a0[1].x); o0[5] = f2bf(a0[1].y);
            o0[6] = f2bf(a0[1].z); o0[7] = f2bf(a0[1].w);
            o1[0] = f2bf(a0[2].x); o1[1] = f2bf(a0[2].y);
            o1[2] = f2bf(a0[2].z); o1[3] = f2bf(a0[2].w);
            o1[4] = f2bf(a0[3].x); o1[5] = f2bf(a0[3].y);
            o1[6] = f2bf(a0[3].z); o1[7] = f2bf(a0[3].w);
            ushort8* Yo = Y + (size_t)row0 * 8 + q * 2;
            Yo[0] = o0;
            Yo[1] = o1;
        }
        if (row1 < n) {
            ushort8 o0, o1;
            o0[0] = f2bf(a1[0].x); o0[1] = f2bf(a1[0].y);
            o0[2] = f2bf(a1[0].z); o0[3] = f2bf(a1[0].w);
            o0[4] = f2bf(a1[1].x); o0[5] = f2bf(a1[1].y);
            o0[6] = f2bf(a1[1].z); o0[7] = f2bf(a1[1].w);
            o1[0] = f2bf(a1[2].x); o1[1] = f2bf(a1[2].y);
            o1[2] = f2bf(a1[2].z); o1[3] = f2bf(a1[2].w);
            o1[4] = f2bf(a1[3].x); o1[5] = f2bf(a1[3].y);
            o1[6] = f2bf(a1[3].z); o1[7] = f2bf(a1[3].w);
            ushort8* Yo = Y + (size_t)row1 * 8 + q * 2;
            Yo[0] = o0;
            Yo[1] = o1;
        }
    }
}

// ---------------------------------------------------------------------------
// 2) binB: per-superbucket counting sort into CSR order (block-private dense
//    region, native int LDS atomics only). Emits row_beg/row_end/dis.
// ---------------------------------------------------------------------------
__global__ void binB_kernel(const int* __restrict__ sbcursor, const int* __restrict__ packed,
                            int* __restrict__ csr_col, int* __restrict__ row_beg,
                            int* __restrict__ row_end, float* __restrict__ dis, int n) {
    __shared__ int rcnt[SBROWS];
    __shared__ int rcur[SBROWS];
    int sb = blockIdx.x;
    int t = threadIdx.x;
    int cnt = min(sbcursor[sb * CURPAD], CAP);
    const int* pk = packed + ((size_t)sb << CAPSHIFT);
    for (int i = t; i < SBROWS; i += 256) rcnt[i] = 0;
    __syncthreads();
    for (int i = t; i < cnt; i += 256) atomicAdd(&rcnt[pk[i] >> 17], 1);
    __syncthreads();
    // exclusive scan of rcnt[512] by wave 0 (8 elems/lane + shfl_up scan)
    if (t < 64) {
        int v[8];
        int run = 0;
#pragma unroll
        for (int k = 0; k < 8; k++) { v[k] = run; run += rcnt[t * 8 + k]; }
        int x = run;
        for (int off = 1; off < 64; off <<= 1) {
            int y = __shfl_up(x, off);
            if (t >= off) x += y;
        }
        int excl = x - run;
#pragma unroll
        for (int k = 0; k < 8; k++) rcur[t * 8 + k] = excl + v[k];
    }
    __syncthreads();
    int rows = min(SBROWS, n - sb * SBROWS);
    for (int rl = t; rl < rows; rl += 256) {
        int beg = (sb << CAPSHIFT) + rcur[rl];
        int d = rcnt[rl];
        int r = sb * SBROWS + rl;
        row_beg[r] = beg;
        row_end[r] = beg + d;
        dis[r] = (d > 0) ? rsqrtf((float)d) : 0.0f;
    }
    __syncthreads();
    for (int i = t; i < cnt; i += 256) {
        int p = pk[i];
        int pos = atomicAdd(&rcur[p >> 17], 1);
        csr_col[(sb << CAPSHIFT) + pos] = p & 0x1FFFF;
    }
}

// ---------------------------------------------------------------------------
// 3) spmm: TWO rows per wave (one per 32-lane half) for 2x independent gather
//    chains. Within a half: 4 edge slots (sub) x 8 feat chunks (f8, 16 B bf16
//    loads). Register accumulate, half-local shfl_xor reduce, fused
//    dis[row]/bias/relu epilogue. Zero atomics.
// ---------------------------------------------------------------------------
__global__ __launch_bounds__(256) void spmm_kernel(
        const int* __restrict__ row_beg, const int* __restrict__ row_end,
        const int* __restrict__ csr_col, const float* __restrict__ dis,
        const ushort8* __restrict__ Y, const float* __restrict__ bias,
        float* __restrict__ out, int n) {
    int wid = (int)(((long long)blockIdx.x * blockDim.x + threadIdx.x) >> 6);
    int lane = threadIdx.x & 63;
    int h = lane >> 5;            // which of the wave's two rows
    int lane5 = lane & 31;
    int hbase = h << 5;
    int row = wid * 2 + h;
    bool active = row < n;
    int s = active ? row_beg[row] : 0;
    int e = active ? row_end[row] : 0;
    int sub = lane5 >> 3;         // edge slot 0..3
    int f8 = lane5 & 7;           // feat chunk 0..7
    float acc[8] = {0.f, 0.f, 0.f, 0.f, 0.f, 0.f, 0.f, 0.f};
    for (int base = s; base < e; base += 32) {
        int cnt = min(32, e - base);
        int c = 0;
        float dv = 0.f;
        if (lane5 < cnt) { c = csr_col[base + lane5]; dv = dis[c]; }
        for (int i = 0; i < cnt; i += 4) {
            int idx = i + sub;
            int ce = __shfl(c, hbase + idx);
            float de = __shfl(dv, hbase + idx);
            if (idx < cnt) {
                ushort8 y = Y[(size_t)ce * 8 + f8];
#pragma unroll
                for (int k = 0; k < 8; k++)
                    acc[k] = fmaf(de, __uint_as_float(((unsigned)y[k]) << 16), acc[k]);
            }
        }
    }
    // reduce across the 4 edge slots (bits 3,4 — stays within the half)
#pragma unroll
    for (int k = 0; k < 8; k++) {
        acc[k] += __shfl_xor(acc[k], 8);
        acc[k] += __shfl_xor(acc[k], 16);
    }
    if (active && sub == 0) {
        float dr = dis[row];
        float4 b0 = ((const float4*)bias)[f8 * 2];
        float4 b1 = ((const float4*)bias)[f8 * 2 + 1];
        float4 o0, o1;
        o0.x = fmaxf(fmaf(dr, acc[0], b0.x), 0.f);
        o0.y = fmaxf(fmaf(dr, acc[1], b0.y), 0.f);
        o0.z = fmaxf(fmaf(dr, acc[2], b0.z), 0.f);
        o0.w = fmaxf(fmaf(dr, acc[3], b0.w), 0.f);
        o1.x = fmaxf(fmaf(dr, acc[4], b1.x), 0.f);
        o1.y = fmaxf(fmaf(dr, acc[5], b1.y), 0.f);
        o1.z = fmaxf(fmaf(dr, acc[6], b1.z), 0.f);
        o1.w = fmaxf(fmaf(dr, acc[7], b1.w), 0.f);
        float4* op = (float4*)(out + (size_t)row * DFEAT + f8 * 8);
        op[0] = o0;
        op[1] = o1;
    }
}

// ---------------------------------------------------------------------------
extern "C" void kernel_launch(void* const* d_in, const int* in_sizes, int n_in,
                              void* d_out, int out_size, void* d_ws, size_t ws_size,
                              hipStream_t stream) {
    const float* feat = (const float*)d_in[0];   // [N, 64] f32
    const int*   ei   = (const int*)d_in[1];     // [2, E] int32 (rows then cols)
    const float* W    = (const float*)d_in[2];   // [64, 64] f32
    const float* bias = (const float*)d_in[3];   // [64] f32
    float* out = (float*)d_out;                  // [N, 64] f32

    int n = in_sizes[0] / DFEAT;                 // 100000
    int E = in_sizes[1] / 2;                     // 1250000
    int nSB = (n + SBROWS - 1) >> SBSHIFT;       // 196

    // workspace layout (int units; every region 16B-aligned):
    int* ws = (int*)d_ws;
    size_t o = 0;
    int*   sbcursor = ws + o; o += 256 * CURPAD; // padded: 1 counter / 64B line
    float* dis      = (float*)(ws + o); o += (size_t)n;
    int*   row_beg  = ws + o; o += (size_t)n;
    int*   row_end  = ws + o; o += (size_t)n;
    int*   packed   = ws + o; o += (size_t)nSB << CAPSHIFT;
    int*   csr_col  = ws + o; o += (size_t)nSB << CAPSHIFT;
    ushort8* Y      = (ushort8*)(ws + o);        // n * 64 bf16 = n*16 ints

    hipMemsetAsync(sbcursor, 0, 256 * CURPAD * sizeof(int), stream);

    int binABlocks = (E + CHUNK - 1) / CHUNK;    // 153
    int xwBlocks = (n + 127) / 128;              // 782
    binA_xw_kernel<<<binABlocks + xwBlocks, 256, 0, stream>>>(
        feat, W, Y, n, ei, E, sbcursor, packed, binABlocks);
    binB_kernel<<<nSB, 256, 0, stream>>>(sbcursor, packed, csr_col, row_beg, row_end, dis, n);
    spmm_kernel<<<((n + 1) / 2 + 3) / 4, 256, 0, stream>>>(
        row_beg, row_end, csr_col, dis, Y, bias, out, n);
}

// Round 12
// 166.824 us; speedup vs baseline: 4.2746x; 4.2746x over previous
//
#include <hip/hip_runtime.h>
#include <hip/hip_bf16.h>

#define DFEAT 64
#define SBSHIFT 9            // 512 rows per superbucket
#define SBROWS 512
#define CAPSHIFT 13          // 8192 edge slots per superbucket region
#define CAP 8192
#define CHUNK 4096           // edges per binA block (R10 measured-good)
#define RPT 16               // CHUNK/256
#define CURPAD 16            // sbcursor padded: one counter per 64B line

typedef __attribute__((ext_vector_type(8))) unsigned short ushort8;

static __device__ __forceinline__ unsigned short f2bf(float f) {
    __hip_bfloat16 h = __float2bfloat16(f);   // RNE
    unsigned short u;
    __builtin_memcpy(&u, &h, 2);
    return u;
}

// ---------------------------------------------------------------------------
// 1) FUSED: binA (blocks [0,binABlocks) — FIRST, overlapping xw) || xw.
//    LDS union: binA 2 KB (hist+cur), xw 16 KB (W).
//    binA: LDS histogram over 512-row superbuckets -> one global atomicAdd
//    per (block,sb) on padded cursors -> direct scatter,
//    payload = (row&511)<<17 | col. Rows held in registers between passes.
//    xw: Y[t] = feat[t] @ W in bf16, quad-cooperative; TWO rows per thread
//    via a #pragma unroll 1 LOOP (registers reused per iteration — R11's
//    dual-stream version hit 256 VGPR + scratch spill; this must stay ~80).
// ---------------------------------------------------------------------------
__global__ __launch_bounds__(256) void binA_xw_kernel(
        const float* __restrict__ feat, const float* __restrict__ W,
        ushort8* __restrict__ Y, int n,
        const int* __restrict__ ei, int E,
        int* __restrict__ sbcursor, int* __restrict__ packed, int binABlocks) {
    __shared__ __align__(16) char smem[16384];

    if (blockIdx.x < binABlocks) {
        // ---------------- binA part ----------------
        int* hist = (int*)smem;        // 256
        int* cur  = hist + 256;        // 256
        int t = threadIdx.x;
        hist[t] = 0;
        __syncthreads();

        int base = blockIdx.x * CHUNK;
        int rv[RPT];
#pragma unroll
        for (int k = 0; k < RPT; k++) {
            int idx = base + k * 256 + t;
            rv[k] = (idx < E) ? ei[idx] : -1;
            if (rv[k] >= 0) atomicAdd(&hist[rv[k] >> SBSHIFT], 1);
        }
        __syncthreads();

        int h = hist[t];
        cur[t] = (h > 0) ? atomicAdd(&sbcursor[t * CURPAD], h) : 0;  // absolute base
        __syncthreads();

#pragma unroll
        for (int k = 0; k < RPT; k++) {
            int idx = base + k * 256 + t;
            if (rv[k] >= 0) {
                int r = rv[k];
                int c = ei[E + idx];
                int sb = r >> SBSHIFT;
                int pos = atomicAdd(&cur[sb], 1);
                if (pos < CAP)
                    packed[(sb << CAPSHIFT) + pos] = ((r & (SBROWS - 1)) << 17) | c;
            }
        }
    } else {
        // ---------------- xw part (2 rows/thread via loop) ----------------
        float4* sW = (float4*)smem;    // 16 KB: W[k][j] as float4 over j
        for (int i = threadIdx.x; i < DFEAT * 16; i += blockDim.x)
            sW[i] = ((const float4*)W)[i];
        __syncthreads();

        int bid = blockIdx.x - binABlocks;
        int q = threadIdx.x & 3;
        int lrow = threadIdx.x >> 2;
        int lane = threadIdx.x & 63;
        int qbase = lane & ~3;

#pragma unroll 1
        for (int rr = 0; rr < 2; rr++) {
            int row = bid * 128 + rr * 64 + lrow;

            float4 x[4];
            if (row < n) {
                const float4* xp = (const float4*)(feat + (size_t)row * DFEAT) + q * 4;
                x[0] = xp[0]; x[1] = xp[1]; x[2] = xp[2]; x[3] = xp[3];
            } else {
                x[0] = x[1] = x[2] = x[3] = make_float4(0.f, 0.f, 0.f, 0.f);
            }

            float4 acc[4];
#pragma unroll
            for (int j = 0; j < 4; j++) acc[j] = make_float4(0.f, 0.f, 0.f, 0.f);

#pragma unroll
            for (int qp = 0; qp < 4; qp++) {
#pragma unroll
                for (int jj = 0; jj < 4; jj++) {
                    float xs[4];
                    xs[0] = __shfl(x[jj].x, qbase + qp);
                    xs[1] = __shfl(x[jj].y, qbase + qp);
                    xs[2] = __shfl(x[jj].z, qbase + qp);
                    xs[3] = __shfl(x[jj].w, qbase + qp);
                    int k0 = qp * 16 + jj * 4;
#pragma unroll
                    for (int c = 0; c < 4; c++) {
                        const float4* wrow = &sW[(k0 + c) * 16 + q * 4];
#pragma unroll
                        for (int j = 0; j < 4; j++) {
                            float4 w = wrow[j];
                            acc[j].x = fmaf(xs[c], w.x, acc[j].x);
                            acc[j].y = fmaf(xs[c], w.y, acc[j].y);
                            acc[j].z = fmaf(xs[c], w.z, acc[j].z);
                            acc[j].w = fmaf(xs[c], w.w, acc[j].w);
                        }
                    }
                }
            }

            if (row < n) {
                ushort8 o0, o1;
                o0[0] = f2bf(acc[0].x); o0[1] = f2bf(acc[0].y);
                o0[2] = f2bf(acc[0].z); o0[3] = f2bf(acc[0].w);
                o0[4] = f2bf(acc[1].x); o0[5] = f2bf(acc[1].y);
                o0[6] = f2bf(acc[1].z); o0[7] = f2bf(acc[1].w);
                o1[0] = f2bf(acc[2].x); o1[1] = f2bf(acc[2].y);
                o1[2] = f2bf(acc[2].z); o1[3] = f2bf(acc[2].w);
                o1[4] = f2bf(acc[3].x); o1[5] = f2bf(acc[3].y);
                o1[6] = f2bf(acc[3].z); o1[7] = f2bf(acc[3].w);
                ushort8* Yo = Y + (size_t)row * 8 + q * 2;
                Yo[0] = o0;
                Yo[1] = o1;
            }
        }
    }
}

// ---------------------------------------------------------------------------
// 2) binB: per-superbucket counting sort into CSR order (block-private dense
//    region, native int LDS atomics only). Emits row_beg/row_end/dis.
// ---------------------------------------------------------------------------
__global__ void binB_kernel(const int* __restrict__ sbcursor, const int* __restrict__ packed,
                            int* __restrict__ csr_col, int* __restrict__ row_beg,
                            int* __restrict__ row_end, float* __restrict__ dis, int n) {
    __shared__ int rcnt[SBROWS];
    __shared__ int rcur[SBROWS];
    int sb = blockIdx.x;
    int t = threadIdx.x;
    int cnt = min(sbcursor[sb * CURPAD], CAP);
    const int* pk = packed + ((size_t)sb << CAPSHIFT);
    for (int i = t; i < SBROWS; i += 256) rcnt[i] = 0;
    __syncthreads();
    for (int i = t; i < cnt; i += 256) atomicAdd(&rcnt[pk[i] >> 17], 1);
    __syncthreads();
    // exclusive scan of rcnt[512] by wave 0 (8 elems/lane + shfl_up scan)
    if (t < 64) {
        int v[8];
        int run = 0;
#pragma unroll
        for (int k = 0; k < 8; k++) { v[k] = run; run += rcnt[t * 8 + k]; }
        int x = run;
        for (int off = 1; off < 64; off <<= 1) {
            int y = __shfl_up(x, off);
            if (t >= off) x += y;
        }
        int excl = x - run;
#pragma unroll
        for (int k = 0; k < 8; k++) rcur[t * 8 + k] = excl + v[k];
    }
    __syncthreads();
    int rows = min(SBROWS, n - sb * SBROWS);
    for (int rl = t; rl < rows; rl += 256) {
        int beg = (sb << CAPSHIFT) + rcur[rl];
        int d = rcnt[rl];
        int r = sb * SBROWS + rl;
        row_beg[r] = beg;
        row_end[r] = beg + d;
        dis[r] = (d > 0) ? rsqrtf((float)d) : 0.0f;
    }
    __syncthreads();
    for (int i = t; i < cnt; i += 256) {
        int p = pk[i];
        int pos = atomicAdd(&rcur[p >> 17], 1);
        csr_col[(sb << CAPSHIFT) + pos] = p & 0x1FFFF;
    }
}

// ---------------------------------------------------------------------------
// 3) spmm: TWO rows per wave (one per 32-lane half) for 2x independent gather
//    chains. Within a half: 4 edge slots (sub) x 8 feat chunks (f8, 16 B bf16
//    loads). Register accumulate, half-local shfl_xor reduce, fused
//    dis[row]/bias/relu epilogue. Zero atomics.
// ---------------------------------------------------------------------------
__global__ __launch_bounds__(256) void spmm_kernel(
        const int* __restrict__ row_beg, const int* __restrict__ row_end,
        const int* __restrict__ csr_col, const float* __restrict__ dis,
        const ushort8* __restrict__ Y, const float* __restrict__ bias,
        float* __restrict__ out, int n) {
    int wid = (int)(((long long)blockIdx.x * blockDim.x + threadIdx.x) >> 6);
    int lane = threadIdx.x & 63;
    int h = lane >> 5;            // which of the wave's two rows
    int lane5 = lane & 31;
    int hbase = h << 5;
    int row = wid * 2 + h;
    bool active = row < n;
    int s = active ? row_beg[row] : 0;
    int e = active ? row_end[row] : 0;
    int sub = lane5 >> 3;         // edge slot 0..3
    int f8 = lane5 & 7;           // feat chunk 0..7
    float acc[8] = {0.f, 0.f, 0.f, 0.f, 0.f, 0.f, 0.f, 0.f};
    for (int base = s; base < e; base += 32) {
        int cnt = min(32, e - base);
        int c = 0;
        float dv = 0.f;
        if (lane5 < cnt) { c = csr_col[base + lane5]; dv = dis[c]; }
        for (int i = 0; i < cnt; i += 4) {
            int idx = i + sub;
            int ce = __shfl(c, hbase + idx);
            float de = __shfl(dv, hbase + idx);
            if (idx < cnt) {
                ushort8 y = Y[(size_t)ce * 8 + f8];
#pragma unroll
                for (int k = 0; k < 8; k++)
                    acc[k] = fmaf(de, __uint_as_float(((unsigned)y[k]) << 16), acc[k]);
            }
        }
    }
    // reduce across the 4 edge slots (bits 3,4 — stays within the half)
#pragma unroll
    for (int k = 0; k < 8; k++) {
        acc[k] += __shfl_xor(acc[k], 8);
        acc[k] += __shfl_xor(acc[k], 16);
    }
    if (active && sub == 0) {
        float dr = dis[row];
        float4 b0 = ((const float4*)bias)[f8 * 2];
        float4 b1 = ((const float4*)bias)[f8 * 2 + 1];
        float4 o0, o1;
        o0.x = fmaxf(fmaf(dr, acc[0], b0.x), 0.f);
        o0.y = fmaxf(fmaf(dr, acc[1], b0.y), 0.f);
        o0.z = fmaxf(fmaf(dr, acc[2], b0.z), 0.f);
        o0.w = fmaxf(fmaf(dr, acc[3], b0.w), 0.f);
        o1.x = fmaxf(fmaf(dr, acc[4], b1.x), 0.f);
        o1.y = fmaxf(fmaf(dr, acc[5], b1.y), 0.f);
        o1.z = fmaxf(fmaf(dr, acc[6], b1.z), 0.f);
        o1.w = fmaxf(fmaf(dr, acc[7], b1.w), 0.f);
        float4* op = (float4*)(out + (size_t)row * DFEAT + f8 * 8);
        op[0] = o0;
        op[1] = o1;
    }
}

// ---------------------------------------------------------------------------
extern "C" void kernel_launch(void* const* d_in, const int* in_sizes, int n_in,
                              void* d_out, int out_size, void* d_ws, size_t ws_size,
                              hipStream_t stream) {
    const float* feat = (const float*)d_in[0];   // [N, 64] f32
    const int*   ei   = (const int*)d_in[1];     // [2, E] int32 (rows then cols)
    const float* W    = (const float*)d_in[2];   // [64, 64] f32
    const float* bias = (const float*)d_in[3];   // [64] f32
    float* out = (float*)d_out;                  // [N, 64] f32

    int n = in_sizes[0] / DFEAT;                 // 100000
    int E = in_sizes[1] / 2;                     // 1250000
    int nSB = (n + SBROWS - 1) >> SBSHIFT;       // 196

    // workspace layout (int units; every region 16B-aligned):
    int* ws = (int*)d_ws;
    size_t o = 0;
    int*   sbcursor = ws + o; o += 256 * CURPAD; // padded: 1 counter / 64B line
    float* dis      = (float*)(ws + o); o += (size_t)n;
    int*   row_beg  = ws + o; o += (size_t)n;
    int*   row_end  = ws + o; o += (size_t)n;
    int*   packed   = ws + o; o += (size_t)nSB << CAPSHIFT;
    int*   csr_col  = ws + o; o += (size_t)nSB << CAPSHIFT;
    ushort8* Y      = (ushort8*)(ws + o);        // n * 64 bf16 = n*16 ints

    hipMemsetAsync(sbcursor, 0, 256 * CURPAD * sizeof(int), stream);

    int binABlocks = (E + CHUNK - 1) / CHUNK;    // 306
    int xwBlocks = (n + 127) / 128;              // 782
    binA_xw_kernel<<<binABlocks + xwBlocks, 256, 0, stream>>>(
        feat, W, Y, n, ei, E, sbcursor, packed, binABlocks);
    binB_kernel<<<nSB, 256, 0, stream>>>(sbcursor, packed, csr_col, row_beg, row_end, dis, n);
    spmm_kernel<<<((n + 1) / 2 + 3) / 4, 256, 0, stream>>>(
        row_beg, row_end, csr_col, dis, Y, bias, out, n);
}

// Round 13
// 161.468 us; speedup vs baseline: 4.4164x; 1.0332x over previous
//
#include <hip/hip_runtime.h>
#include <hip/hip_bf16.h>

#define DFEAT 64
#define SBSHIFT 9            // 512 rows per superbucket
#define SBROWS 512
#define CAPSHIFT 13          // 8192 edge slots per superbucket region
#define CAP 8192
#define CHUNK 4096           // edges per binA block (R10 measured-good)
#define RPT 16               // CHUNK/256
#define CURPAD 16            // sbcursor padded: one counter per 64B line

typedef __attribute__((ext_vector_type(8))) unsigned short ushort8;

static __device__ __forceinline__ unsigned short f2bf(float f) {
    __hip_bfloat16 h = __float2bfloat16(f);   // RNE
    unsigned short u;
    __builtin_memcpy(&u, &h, 2);
    return u;
}

// ---------------------------------------------------------------------------
// 1) FUSED: binA (blocks [0,binABlocks) — FIRST, overlapping xw) || xw.
//    LDS union: binA 2 KB (hist+cur), xw 16 KB (W).
//    binA: LDS histogram over 512-row superbuckets -> one global atomicAdd
//    per (block,sb) on padded cursors -> direct scatter,
//    payload = (row&511)<<17 | col. Rows held in registers between passes.
//    xw: Y[t] = feat[t] @ W in bf16, quad-cooperative, ONE row per thread
//    (R10 config — 1563 blocks; R11's dual-stream spilled at 256 VGPR,
//    R12's 2-row serial loop lost wave-parallelism. 1 row/thread is best.)
// ---------------------------------------------------------------------------
__global__ __launch_bounds__(256) void binA_xw_kernel(
        const float* __restrict__ feat, const float* __restrict__ W,
        ushort8* __restrict__ Y, int n,
        const int* __restrict__ ei, int E,
        int* __restrict__ sbcursor, int* __restrict__ packed, int binABlocks) {
    __shared__ __align__(16) char smem[16384];

    if (blockIdx.x < binABlocks) {
        // ---------------- binA part ----------------
        int* hist = (int*)smem;        // 256
        int* cur  = hist + 256;        // 256
        int t = threadIdx.x;
        hist[t] = 0;
        __syncthreads();

        int base = blockIdx.x * CHUNK;
        int rv[RPT];
#pragma unroll
        for (int k = 0; k < RPT; k++) {
            int idx = base + k * 256 + t;
            rv[k] = (idx < E) ? ei[idx] : -1;
            if (rv[k] >= 0) atomicAdd(&hist[rv[k] >> SBSHIFT], 1);
        }
        __syncthreads();

        int h = hist[t];
        cur[t] = (h > 0) ? atomicAdd(&sbcursor[t * CURPAD], h) : 0;  // absolute base
        __syncthreads();

#pragma unroll
        for (int k = 0; k < RPT; k++) {
            int idx = base + k * 256 + t;
            if (rv[k] >= 0) {
                int r = rv[k];
                int c = ei[E + idx];
                int sb = r >> SBSHIFT;
                int pos = atomicAdd(&cur[sb], 1);
                if (pos < CAP)
                    packed[(sb << CAPSHIFT) + pos] = ((r & (SBROWS - 1)) << 17) | c;
            }
        }
    } else {
        // ---------------- xw part (1 row/thread, R10) ----------------
        float4* sW = (float4*)smem;    // 16 KB: W[k][j] as float4 over j
        for (int i = threadIdx.x; i < DFEAT * 16; i += blockDim.x)
            sW[i] = ((const float4*)W)[i];
        __syncthreads();

        int bid = blockIdx.x - binABlocks;
        int q = threadIdx.x & 3;
        int lrow = threadIdx.x >> 2;
        int lane = threadIdx.x & 63;
        int qbase = lane & ~3;
        int row = bid * 64 + lrow;

        float4 x[4];
        if (row < n) {
            const float4* xp = (const float4*)(feat + (size_t)row * DFEAT) + q * 4;
            x[0] = xp[0]; x[1] = xp[1]; x[2] = xp[2]; x[3] = xp[3];
        } else {
            x[0] = x[1] = x[2] = x[3] = make_float4(0.f, 0.f, 0.f, 0.f);
        }

        float4 acc[4];
#pragma unroll
        for (int j = 0; j < 4; j++) acc[j] = make_float4(0.f, 0.f, 0.f, 0.f);

#pragma unroll
        for (int qp = 0; qp < 4; qp++) {
#pragma unroll
            for (int jj = 0; jj < 4; jj++) {
                float xs[4];
                xs[0] = __shfl(x[jj].x, qbase + qp);
                xs[1] = __shfl(x[jj].y, qbase + qp);
                xs[2] = __shfl(x[jj].z, qbase + qp);
                xs[3] = __shfl(x[jj].w, qbase + qp);
                int k0 = qp * 16 + jj * 4;
#pragma unroll
                for (int c = 0; c < 4; c++) {
                    const float4* wrow = &sW[(k0 + c) * 16 + q * 4];
#pragma unroll
                    for (int j = 0; j < 4; j++) {
                        float4 w = wrow[j];
                        acc[j].x = fmaf(xs[c], w.x, acc[j].x);
                        acc[j].y = fmaf(xs[c], w.y, acc[j].y);
                        acc[j].z = fmaf(xs[c], w.z, acc[j].z);
                        acc[j].w = fmaf(xs[c], w.w, acc[j].w);
                    }
                }
            }
        }

        if (row < n) {
            ushort8 o0, o1;
            o0[0] = f2bf(acc[0].x); o0[1] = f2bf(acc[0].y);
            o0[2] = f2bf(acc[0].z); o0[3] = f2bf(acc[0].w);
            o0[4] = f2bf(acc[1].x); o0[5] = f2bf(acc[1].y);
            o0[6] = f2bf(acc[1].z); o0[7] = f2bf(acc[1].w);
            o1[0] = f2bf(acc[2].x); o1[1] = f2bf(acc[2].y);
            o1[2] = f2bf(acc[2].z); o1[3] = f2bf(acc[2].w);
            o1[4] = f2bf(acc[3].x); o1[5] = f2bf(acc[3].y);
            o1[6] = f2bf(acc[3].z); o1[7] = f2bf(acc[3].w);
            ushort8* Yo = Y + (size_t)row * 8 + q * 2;
            Yo[0] = o0;
            Yo[1] = o1;
        }
    }
}

// ---------------------------------------------------------------------------
// 2) binB: per-superbucket counting sort into CSR order (block-private dense
//    region, native int LDS atomics only). Emits row_beg/row_end/dis.
// ---------------------------------------------------------------------------
__global__ void binB_kernel(const int* __restrict__ sbcursor, const int* __restrict__ packed,
                            int* __restrict__ csr_col, int* __restrict__ row_beg,
                            int* __restrict__ row_end, float* __restrict__ dis, int n) {
    __shared__ int rcnt[SBROWS];
    __shared__ int rcur[SBROWS];
    int sb = blockIdx.x;
    int t = threadIdx.x;
    int cnt = min(sbcursor[sb * CURPAD], CAP);
    const int* pk = packed + ((size_t)sb << CAPSHIFT);
    for (int i = t; i < SBROWS; i += 256) rcnt[i] = 0;
    __syncthreads();
    for (int i = t; i < cnt; i += 256) atomicAdd(&rcnt[pk[i] >> 17], 1);
    __syncthreads();
    // exclusive scan of rcnt[512] by wave 0 (8 elems/lane + shfl_up scan)
    if (t < 64) {
        int v[8];
        int run = 0;
#pragma unroll
        for (int k = 0; k < 8; k++) { v[k] = run; run += rcnt[t * 8 + k]; }
        int x = run;
        for (int off = 1; off < 64; off <<= 1) {
            int y = __shfl_up(x, off);
            if (t >= off) x += y;
        }
        int excl = x - run;
#pragma unroll
        for (int k = 0; k < 8; k++) rcur[t * 8 + k] = excl + v[k];
    }
    __syncthreads();
    int rows = min(SBROWS, n - sb * SBROWS);
    for (int rl = t; rl < rows; rl += 256) {
        int beg = (sb << CAPSHIFT) + rcur[rl];
        int d = rcnt[rl];
        int r = sb * SBROWS + rl;
        row_beg[r] = beg;
        row_end[r] = beg + d;
        dis[r] = (d > 0) ? rsqrtf((float)d) : 0.0f;
    }
    __syncthreads();
    for (int i = t; i < cnt; i += 256) {
        int p = pk[i];
        int pos = atomicAdd(&rcur[p >> 17], 1);
        csr_col[(sb << CAPSHIFT) + pos] = p & 0x1FFFF;
    }
}

// ---------------------------------------------------------------------------
// 3) spmm: TWO rows per wave (one per 32-lane half). Within a half: 4 edge
//    slots (sub) x 8 feat chunks (f8, 16 B bf16 loads). Inner loop is
//    GUARD-FREE: lanes >= cnt hold c=0/dv=0, so shfl'd tail slots gather
//    Y[0] (L1-hot) and fma adds 0 — no exec-mask churn, all gathers issue
//    back-to-back (MLP). Register accumulate, half-local shfl_xor reduce,
//    fused dis[row]/bias/relu epilogue. Zero atomics.
// ---------------------------------------------------------------------------
__global__ __launch_bounds__(256) void spmm_kernel(
        const int* __restrict__ row_beg, const int* __restrict__ row_end,
        const int* __restrict__ csr_col, const float* __restrict__ dis,
        const ushort8* __restrict__ Y, const float* __restrict__ bias,
        float* __restrict__ out, int n) {
    int wid = (int)(((long long)blockIdx.x * blockDim.x + threadIdx.x) >> 6);
    int lane = threadIdx.x & 63;
    int h = lane >> 5;            // which of the wave's two rows
    int lane5 = lane & 31;
    int hbase = h << 5;
    int row = wid * 2 + h;
    bool active = row < n;
    int s = active ? row_beg[row] : 0;
    int e = active ? row_end[row] : 0;
    int sub = lane5 >> 3;         // edge slot 0..3
    int f8 = lane5 & 7;           // feat chunk 0..7
    float acc[8] = {0.f, 0.f, 0.f, 0.f, 0.f, 0.f, 0.f, 0.f};
    for (int base = s; base < e; base += 32) {
        int cnt = min(32, e - base);
        int c = 0;
        float dv = 0.f;
        if (lane5 < cnt) { c = csr_col[base + lane5]; dv = dis[c]; }
        for (int i = 0; i < cnt; i += 4) {
            int ce = __shfl(c, hbase + i + sub);     // tail slots -> lane with c=0
            float de = __shfl(dv, hbase + i + sub);  // -> 0.0f
            ushort8 y = Y[(size_t)ce * 8 + f8];
#pragma unroll
            for (int k = 0; k < 8; k++)
                acc[k] = fmaf(de, __uint_as_float(((unsigned)y[k]) << 16), acc[k]);
        }
    }
    // reduce across the 4 edge slots (bits 3,4 — stays within the half)
#pragma unroll
    for (int k = 0; k < 8; k++) {
        acc[k] += __shfl_xor(acc[k], 8);
        acc[k] += __shfl_xor(acc[k], 16);
    }
    if (active && sub == 0) {
        float dr = dis[row];
        float4 b0 = ((const float4*)bias)[f8 * 2];
        float4 b1 = ((const float4*)bias)[f8 * 2 + 1];
        float4 o0, o1;
        o0.x = fmaxf(fmaf(dr, acc[0], b0.x), 0.f);
        o0.y = fmaxf(fmaf(dr, acc[1], b0.y), 0.f);
        o0.z = fmaxf(fmaf(dr, acc[2], b0.z), 0.f);
        o0.w = fmaxf(fmaf(dr, acc[3], b0.w), 0.f);
        o1.x = fmaxf(fmaf(dr, acc[4], b1.x), 0.f);
        o1.y = fmaxf(fmaf(dr, acc[5], b1.y), 0.f);
        o1.z = fmaxf(fmaf(dr, acc[6], b1.z), 0.f);
        o1.w = fmaxf(fmaf(dr, acc[7], b1.w), 0.f);
        float4* op = (float4*)(out + (size_t)row * DFEAT + f8 * 8);
        op[0] = o0;
        op[1] = o1;
    }
}

// ---------------------------------------------------------------------------
extern "C" void kernel_launch(void* const* d_in, const int* in_sizes, int n_in,
                              void* d_out, int out_size, void* d_ws, size_t ws_size,
                              hipStream_t stream) {
    const float* feat = (const float*)d_in[0];   // [N, 64] f32
    const int*   ei   = (const int*)d_in[1];     // [2, E] int32 (rows then cols)
    const float* W    = (const float*)d_in[2];   // [64, 64] f32
    const float* bias = (const float*)d_in[3];   // [64] f32
    float* out = (float*)d_out;                  // [N, 64] f32

    int n = in_sizes[0] / DFEAT;                 // 100000
    int E = in_sizes[1] / 2;                     // 1250000
    int nSB = (n + SBROWS - 1) >> SBSHIFT;       // 196

    // workspace layout (int units; every region 16B-aligned):
    int* ws = (int*)d_ws;
    size_t o = 0;
    int*   sbcursor = ws + o; o += 256 * CURPAD; // padded: 1 counter / 64B line
    float* dis      = (float*)(ws + o); o += (size_t)n;
    int*   row_beg  = ws + o; o += (size_t)n;
    int*   row_end  = ws + o; o += (size_t)n;
    int*   packed   = ws + o; o += (size_t)nSB << CAPSHIFT;
    int*   csr_col  = ws + o; o += (size_t)nSB << CAPSHIFT;
    ushort8* Y      = (ushort8*)(ws + o);        // n * 64 bf16 = n*16 ints

    hipMemsetAsync(sbcursor, 0, 256 * CURPAD * sizeof(int), stream);

    int binABlocks = (E + CHUNK - 1) / CHUNK;    // 306
    int xwBlocks = (n + 63) / 64;                // 1563
    binA_xw_kernel<<<binABlocks + xwBlocks, 256, 0, stream>>>(
        feat, W, Y, n, ei, E, sbcursor, packed, binABlocks);
    binB_kernel<<<nSB, 256, 0, stream>>>(sbcursor, packed, csr_col, row_beg, row_end, dis, n);
    spmm_kernel<<<((n + 1) / 2 + 3) / 4, 256, 0, stream>>>(
        row_beg, row_end, csr_col, dis, Y, bias, out, n);
}

// Round 14
// 160.229 us; speedup vs baseline: 4.4506x; 1.0077x over previous
//
#include <hip/hip_runtime.h>
#include <hip/hip_bf16.h>

#define DFEAT 64
#define SBSHIFT 9            // 512 rows per superbucket
#define SBROWS 512
#define CAPSHIFT 13          // 8192 edge slots per superbucket region
#define CAP 8192
#define CHUNK 4096           // edges per binA block (R10 measured-good)
#define RPT 16               // CHUNK/256
#define CURPAD 16            // sbcursor padded: one counter per 64B line

typedef __attribute__((ext_vector_type(8))) unsigned short ushort8;

static __device__ __forceinline__ unsigned short f2bf(float f) {
    __hip_bfloat16 h = __float2bfloat16(f);   // RNE
    unsigned short u;
    __builtin_memcpy(&u, &h, 2);
    return u;
}

// ---------------------------------------------------------------------------
// 1) FUSED: binA (blocks [0,binABlocks) — FIRST, overlapping xw) || xw.
//    LDS union: binA 2 KB (hist+cur), xw 16 KB (W).
//    binA: LDS histogram over 512-row superbuckets -> one global atomicAdd
//    per (block,sb) on padded cursors -> direct scatter,
//    payload = (row&511)<<17 | col. Rows held in registers between passes.
//    xw: Y[t] = feat[t] @ W in bf16, quad-cooperative, ONE row per thread
//    (R10 config — R11 dual-stream spilled @256 VGPR; R12 2-row loop lost
//    wave-parallelism. 1 row/thread, 1563 blocks is the measured optimum.)
// ---------------------------------------------------------------------------
__global__ __launch_bounds__(256) void binA_xw_kernel(
        const float* __restrict__ feat, const float* __restrict__ W,
        ushort8* __restrict__ Y, int n,
        const int* __restrict__ ei, int E,
        int* __restrict__ sbcursor, int* __restrict__ packed, int binABlocks) {
    __shared__ __align__(16) char smem[16384];

    if (blockIdx.x < binABlocks) {
        // ---------------- binA part ----------------
        int* hist = (int*)smem;        // 256
        int* cur  = hist + 256;        // 256
        int t = threadIdx.x;
        hist[t] = 0;
        __syncthreads();

        int base = blockIdx.x * CHUNK;
        int rv[RPT];
#pragma unroll
        for (int k = 0; k < RPT; k++) {
            int idx = base + k * 256 + t;
            rv[k] = (idx < E) ? ei[idx] : -1;
            if (rv[k] >= 0) atomicAdd(&hist[rv[k] >> SBSHIFT], 1);
        }
        __syncthreads();

        int h = hist[t];
        cur[t] = (h > 0) ? atomicAdd(&sbcursor[t * CURPAD], h) : 0;  // absolute base
        __syncthreads();

#pragma unroll
        for (int k = 0; k < RPT; k++) {
            int idx = base + k * 256 + t;
            if (rv[k] >= 0) {
                int r = rv[k];
                int c = ei[E + idx];
                int sb = r >> SBSHIFT;
                int pos = atomicAdd(&cur[sb], 1);
                if (pos < CAP)
                    packed[(sb << CAPSHIFT) + pos] = ((r & (SBROWS - 1)) << 17) | c;
            }
        }
    } else {
        // ---------------- xw part (1 row/thread, R10) ----------------
        float4* sW = (float4*)smem;    // 16 KB: W[k][j] as float4 over j
        for (int i = threadIdx.x; i < DFEAT * 16; i += blockDim.x)
            sW[i] = ((const float4*)W)[i];
        __syncthreads();

        int bid = blockIdx.x - binABlocks;
        int q = threadIdx.x & 3;
        int lrow = threadIdx.x >> 2;
        int lane = threadIdx.x & 63;
        int qbase = lane & ~3;
        int row = bid * 64 + lrow;

        float4 x[4];
        if (row < n) {
            const float4* xp = (const float4*)(feat + (size_t)row * DFEAT) + q * 4;
            x[0] = xp[0]; x[1] = xp[1]; x[2] = xp[2]; x[3] = xp[3];
        } else {
            x[0] = x[1] = x[2] = x[3] = make_float4(0.f, 0.f, 0.f, 0.f);
        }

        float4 acc[4];
#pragma unroll
        for (int j = 0; j < 4; j++) acc[j] = make_float4(0.f, 0.f, 0.f, 0.f);

#pragma unroll
        for (int qp = 0; qp < 4; qp++) {
#pragma unroll
            for (int jj = 0; jj < 4; jj++) {
                float xs[4];
                xs[0] = __shfl(x[jj].x, qbase + qp);
                xs[1] = __shfl(x[jj].y, qbase + qp);
                xs[2] = __shfl(x[jj].z, qbase + qp);
                xs[3] = __shfl(x[jj].w, qbase + qp);
                int k0 = qp * 16 + jj * 4;
#pragma unroll
                for (int c = 0; c < 4; c++) {
                    const float4* wrow = &sW[(k0 + c) * 16 + q * 4];
#pragma unroll
                    for (int j = 0; j < 4; j++) {
                        float4 w = wrow[j];
                        acc[j].x = fmaf(xs[c], w.x, acc[j].x);
                        acc[j].y = fmaf(xs[c], w.y, acc[j].y);
                        acc[j].z = fmaf(xs[c], w.z, acc[j].z);
                        acc[j].w = fmaf(xs[c], w.w, acc[j].w);
                    }
                }
            }
        }

        if (row < n) {
            ushort8 o0, o1;
            o0[0] = f2bf(acc[0].x); o0[1] = f2bf(acc[0].y);
            o0[2] = f2bf(acc[0].z); o0[3] = f2bf(acc[0].w);
            o0[4] = f2bf(acc[1].x); o0[5] = f2bf(acc[1].y);
            o0[6] = f2bf(acc[1].z); o0[7] = f2bf(acc[1].w);
            o1[0] = f2bf(acc[2].x); o1[1] = f2bf(acc[2].y);
            o1[2] = f2bf(acc[2].z); o1[3] = f2bf(acc[2].w);
            o1[4] = f2bf(acc[3].x); o1[5] = f2bf(acc[3].y);
            o1[6] = f2bf(acc[3].z); o1[7] = f2bf(acc[3].w);
            ushort8* Yo = Y + (size_t)row * 8 + q * 2;
            Yo[0] = o0;
            Yo[1] = o1;
        }
    }
}

// ---------------------------------------------------------------------------
// 2) binB: per-superbucket counting sort into CSR order (block-private dense
//    region, native int LDS atomics only). Emits row_beg/row_end/dis.
// ---------------------------------------------------------------------------
__global__ void binB_kernel(const int* __restrict__ sbcursor, const int* __restrict__ packed,
                            int* __restrict__ csr_col, int* __restrict__ row_beg,
                            int* __restrict__ row_end, float* __restrict__ dis, int n) {
    __shared__ int rcnt[SBROWS];
    __shared__ int rcur[SBROWS];
    int sb = blockIdx.x;
    int t = threadIdx.x;
    int cnt = min(sbcursor[sb * CURPAD], CAP);
    const int* pk = packed + ((size_t)sb << CAPSHIFT);
    for (int i = t; i < SBROWS; i += 256) rcnt[i] = 0;
    __syncthreads();
    for (int i = t; i < cnt; i += 256) atomicAdd(&rcnt[pk[i] >> 17], 1);
    __syncthreads();
    // exclusive scan of rcnt[512] by wave 0 (8 elems/lane + shfl_up scan)
    if (t < 64) {
        int v[8];
        int run = 0;
#pragma unroll
        for (int k = 0; k < 8; k++) { v[k] = run; run += rcnt[t * 8 + k]; }
        int x = run;
        for (int off = 1; off < 64; off <<= 1) {
            int y = __shfl_up(x, off);
            if (t >= off) x += y;
        }
        int excl = x - run;
#pragma unroll
        for (int k = 0; k < 8; k++) rcur[t * 8 + k] = excl + v[k];
    }
    __syncthreads();
    int rows = min(SBROWS, n - sb * SBROWS);
    for (int rl = t; rl < rows; rl += 256) {
        int beg = (sb << CAPSHIFT) + rcur[rl];
        int d = rcnt[rl];
        int r = sb * SBROWS + rl;
        row_beg[r] = beg;
        row_end[r] = beg + d;
        dis[r] = (d > 0) ? rsqrtf((float)d) : 0.0f;
    }
    __syncthreads();
    for (int i = t; i < cnt; i += 256) {
        int p = pk[i];
        int pos = atomicAdd(&rcur[p >> 17], 1);
        csr_col[(sb << CAPSHIFT) + pos] = p & 0x1FFFF;
    }
}

// ---------------------------------------------------------------------------
// 3) spmm: FOUR rows per wave (one per 16-lane quarter) — with mean degree
//    ~12.5, a 16-lane row unit wastes far fewer csr loads (22% vs 61%) and
//    gather tail slots (~8% vs ~22%) than the old 32-lane unit, and gives 4
//    independent gather chains per wave. Quarter layout: 2 edge slots (sub)
//    x 8 feat chunks (f8, 16 B bf16 loads). Guard-free inner loop (tail
//    slots shfl from lanes holding c=0/dv=0 -> Y[0] gather, fma adds 0).
//    Register accumulate, quarter-local shfl_xor reduce, fused
//    dis[row]/bias/relu epilogue. Zero atomics.
// ---------------------------------------------------------------------------
__global__ __launch_bounds__(256) void spmm_kernel(
        const int* __restrict__ row_beg, const int* __restrict__ row_end,
        const int* __restrict__ csr_col, const float* __restrict__ dis,
        const ushort8* __restrict__ Y, const float* __restrict__ bias,
        float* __restrict__ out, int n) {
    int wid = (int)(((long long)blockIdx.x * blockDim.x + threadIdx.x) >> 6);
    int lane = threadIdx.x & 63;
    int h = lane >> 4;            // which of the wave's four rows (0..3)
    int lq = lane & 15;           // lane within quarter
    int qb = h << 4;              // quarter base lane
    int row = wid * 4 + h;
    bool active = row < n;
    int s = active ? row_beg[row] : 0;
    int e = active ? row_end[row] : 0;
    int sub = lq >> 3;            // edge slot 0..1
    int f8 = lane & 7;            // feat chunk 0..7
    float acc[8] = {0.f, 0.f, 0.f, 0.f, 0.f, 0.f, 0.f, 0.f};
    for (int base = s; base < e; base += 16) {
        int cnt = min(16, e - base);
        int c = 0;
        float dv = 0.f;
        if (lq < cnt) { c = csr_col[base + lq]; dv = dis[c]; }
        for (int i = 0; i < cnt; i += 2) {
            int ce = __shfl(c, qb + i + sub);     // tail slot -> lane with c=0
            float de = __shfl(dv, qb + i + sub);  // -> 0.0f
            ushort8 y = Y[(size_t)ce * 8 + f8];
#pragma unroll
            for (int k = 0; k < 8; k++)
                acc[k] = fmaf(de, __uint_as_float(((unsigned)y[k]) << 16), acc[k]);
        }
    }
    // reduce across the 2 edge slots (bit 3 — stays within the quarter)
#pragma unroll
    for (int k = 0; k < 8; k++)
        acc[k] += __shfl_xor(acc[k], 8);
    if (active && sub == 0) {
        float dr = dis[row];
        float4 b0 = ((const float4*)bias)[f8 * 2];
        float4 b1 = ((const float4*)bias)[f8 * 2 + 1];
        float4 o0, o1;
        o0.x = fmaxf(fmaf(dr, acc[0], b0.x), 0.f);
        o0.y = fmaxf(fmaf(dr, acc[1], b0.y), 0.f);
        o0.z = fmaxf(fmaf(dr, acc[2], b0.z), 0.f);
        o0.w = fmaxf(fmaf(dr, acc[3], b0.w), 0.f);
        o1.x = fmaxf(fmaf(dr, acc[4], b1.x), 0.f);
        o1.y = fmaxf(fmaf(dr, acc[5], b1.y), 0.f);
        o1.z = fmaxf(fmaf(dr, acc[6], b1.z), 0.f);
        o1.w = fmaxf(fmaf(dr, acc[7], b1.w), 0.f);
        float4* op = (float4*)(out + (size_t)row * DFEAT + f8 * 8);
        op[0] = o0;
        op[1] = o1;
    }
}

// ---------------------------------------------------------------------------
extern "C" void kernel_launch(void* const* d_in, const int* in_sizes, int n_in,
                              void* d_out, int out_size, void* d_ws, size_t ws_size,
                              hipStream_t stream) {
    const float* feat = (const float*)d_in[0];   // [N, 64] f32
    const int*   ei   = (const int*)d_in[1];     // [2, E] int32 (rows then cols)
    const float* W    = (const float*)d_in[2];   // [64, 64] f32
    const float* bias = (const float*)d_in[3];   // [64] f32
    float* out = (float*)d_out;                  // [N, 64] f32

    int n = in_sizes[0] / DFEAT;                 // 100000
    int E = in_sizes[1] / 2;                     // 1250000
    int nSB = (n + SBROWS - 1) >> SBSHIFT;       // 196

    // workspace layout (int units; every region 16B-aligned):
    int* ws = (int*)d_ws;
    size_t o = 0;
    int*   sbcursor = ws + o; o += 256 * CURPAD; // padded: 1 counter / 64B line
    float* dis      = (float*)(ws + o); o += (size_t)n;
    int*   row_beg  = ws + o; o += (size_t)n;
    int*   row_end  = ws + o; o += (size_t)n;
    int*   packed   = ws + o; o += (size_t)nSB << CAPSHIFT;
    int*   csr_col  = ws + o; o += (size_t)nSB << CAPSHIFT;
    ushort8* Y      = (ushort8*)(ws + o);        // n * 64 bf16 = n*16 ints

    hipMemsetAsync(sbcursor, 0, 256 * CURPAD * sizeof(int), stream);

    int binABlocks = (E + CHUNK - 1) / CHUNK;    // 306
    int xwBlocks = (n + 63) / 64;                // 1563
    binA_xw_kernel<<<binABlocks + xwBlocks, 256, 0, stream>>>(
        feat, W, Y, n, ei, E, sbcursor, packed, binABlocks);
    binB_kernel<<<nSB, 256, 0, stream>>>(sbcursor, packed, csr_col, row_beg, row_end, dis, n);
    spmm_kernel<<<((n + 3) / 4 + 3) / 4, 256, 0, stream>>>(
        row_beg, row_end, csr_col, dis, Y, bias, out, n);
}